// Round 11
// baseline (154.482 us; speedup 1.0000x reference)
//
#include <hip/hip_runtime.h>
#include <math.h>

// AFM forward: out[b] = linear(b) + softmax-weighted pair-interaction projection.
// B=4096, F=26, d=64, P=325 pairs, af=64.
//
// R11: 2-tile ILP interleave on the R10 structure (2 waves/row, 8192 waves =
// full TLP, end-only merge). R10 post-mortem: last 3 rounds within noise;
// per-wave critical path (ds_read -> MFMA -> fma epilogue -> 2 bpermutes ->
// exp) x 11 serial iters is the remaining kernel-side cost and TLP is maxed.
// This round: each loop body processes TWO independent m-tiles (5 double
// iters + 1 single) so their MFMA/shuffle/exp chains overlap in the wave.
// Staging gather issued before W1-frag preload (longest latency first).
// Measurement round: if bench doesn't move, afm is overhead-dominated.

#define NF 26
#define NP 325
#define NMT 21           // m-tiles of 16 pairs (336; pads contribute e=0)
#define ED 64
#define AF 64
#define NDENSE 13
#define BLOCK 128        // 2 waves, one row per block
#define ESTRIDE 72       // f16 elems per emb row (144 B: 16B-aligned, b128-clean)
#define EBYTES (ESTRIDE * 2)

typedef __attribute__((ext_vector_type(8))) _Float16 half8;
typedef __attribute__((ext_vector_type(4))) float f32x4;

__global__ void prep_kernel(const float* __restrict__ W1,
                            _Float16* __restrict__ w1t)   // [64][64] = W1^T, f16
{
    int t = threadIdx.x;
    for (int idx = t; idx < ED * AF; idx += 256) {
        int d = idx >> 6, a = idx & 63;       // W1 is [d][a]
        w1t[a * ED + d] = (_Float16)W1[idx];
    }
}

__global__ __launch_bounds__(BLOCK, 4)   // VGPR cap 128 (R4/R9 lesson: never cap below live set)
void afm_kernel(const int*   __restrict__ sparse,   // [B,26]
                const float* __restrict__ dense,    // [B,13]
                const float* __restrict__ etab,     // [V,64]
                const float* __restrict__ ltab,     // [V]
                const float* __restrict__ wdense,   // [13]
                const float* __restrict__ bias,     // [1]
                const float* __restrict__ b1,       // [64]
                const float* __restrict__ w2,       // [64]
                const float* __restrict__ proj,     // [64]
                const _Float16* __restrict__ w1t,   // [64][64] f16 (a-major)
                float*       __restrict__ out)      // [B]
{
    const int t    = threadIdx.x;
    const int wave = t >> 6;
    const int lane = t & 63;
    const int qd   = lane >> 4;     // quad 0..3
    const int ln   = lane & 15;
    const int r    = blockIdx.x;    // this block's batch row

    __shared__ alignas(16) _Float16 emb[NF][ESTRIDE];   // 3744 B
    __shared__ float merge[2][2];                       // {rrv, lsum} per wave
    const char* __restrict__ ebase = (const char*)emb;

    // ---- stage this row's 26 embeddings FIRST (longest-latency gather) ----
    const int* __restrict__ srow = sparse + r * NF;
    for (int task = t; task < NF * 8; task += BLOCK) {
        int f = task >> 3, c = task & 7;                 // 8-half chunk
        const float* src = etab + (size_t)srow[f] * ED + c * 8;
        float4 v0 = *(const float4*)(src);
        float4 v1 = *(const float4*)(src + 4);
        half8 h = { (_Float16)v0.x, (_Float16)v0.y, (_Float16)v0.z, (_Float16)v0.w,
                    (_Float16)v1.x, (_Float16)v1.y, (_Float16)v1.z, (_Float16)v1.w };
        *(half8*)(&emb[f][c * 8]) = h;
    }

    // ---- W1^T A-operand fragments (L2-hot 8 KB):
    //      bfr[nt][kh] = w1t[af = nt*16+ln][k = kh*32 + qd*8 + j] ----
    half8 bfr[4][2];
    #pragma unroll
    for (int nt = 0; nt < 4; ++nt)
        #pragma unroll
        for (int kh = 0; kh < 2; ++kh)
            bfr[nt][kh] = *(const half8*)(w1t + (nt * 16 + ln) * ED + kh * 32 + qd * 8);

    // b1/w2 for af = nt*16 + qd*4 + rr  (C-row mapping)
    float4 b1v4[4], w2v4[4];
    #pragma unroll
    for (int nt = 0; nt < 4; ++nt) {
        b1v4[nt] = *(const float4*)(b1 + nt * 16 + qd * 4);
        w2v4[nt] = *(const float4*)(w2 + nt * 16 + qd * 4);
    }

    // ---- linear part (wave 0 registers; lands on t==0 which writes out) ----
    float lin = 0.f;
    if (wave == 0) {
        if (lane < NF) {
            lin = ltab[srow[lane]];
        } else if (lane >= 32 && lane < 32 + NDENSE) {
            int k = lane - 32;
            lin = dense[r * NDENSE + k] * wdense[k];
        }
        #pragma unroll
        for (int off = 32; off >= 1; off >>= 1) lin += __shfl_xor(lin, off, 64);
        lin += bias[0];
    }

    __syncthreads();   // emb visible (couples only 2 waves)

    const int qo0 = qd * 16;            // byte offsets within an emb row
    const int qo1 = 64 + qd * 16;

    float l = 0.f;
    half8 acc0 = { (_Float16)0.f, (_Float16)0.f, (_Float16)0.f, (_Float16)0.f,
                   (_Float16)0.f, (_Float16)0.f, (_Float16)0.f, (_Float16)0.f };
    half8 acc1 = acc0;

    // one m-tile's logit work; x0/x1 returned for the accumulator update
    auto tile_e = [&](int j, half8& x0, half8& x1) -> float {
        const int mt = 2 * j + wave;                // wave1 j=10 -> mt=21: dead, e=0
        const int p  = mt * 16 + ln;
        const int pc = (p < NP) ? p : 0;            // pad-safe decode input
        // closed-form triangular decode (exact in f32 for pc < 325; verified R9)
        const float sq = sqrtf((float)(2601 - 8 * pc));
        const int fi = (int)((51.0f - sq) * 0.5f);
        const int fj = fi + 1 + pc - ((fi * (51 - fi)) >> 1);
        const int oi = fi * EBYTES, oj = fj * EBYTES;

        half8 ei0 = *(const half8*)(ebase + oi + qo0);
        half8 ei1 = *(const half8*)(ebase + oi + qo1);
        half8 ej0 = *(const half8*)(ebase + oj + qo0);
        half8 ej1 = *(const half8*)(ebase + oj + qo1);
        x0 = ei0 * ej0;                             // pair product, in registers
        x1 = ei1 * ej1;

        // logits: D[m=af][n=pair=ln]; C rows = qd*4+reg = af within nt*16
        float lg = 0.f;
        #pragma unroll
        for (int nt = 0; nt < 4; ++nt) {
            f32x4 acc = { b1v4[nt].x, b1v4[nt].y, b1v4[nt].z, b1v4[nt].w };
            acc = __builtin_amdgcn_mfma_f32_16x16x32_f16(bfr[nt][0], x0, acc, 0, 0, 0);
            acc = __builtin_amdgcn_mfma_f32_16x16x32_f16(bfr[nt][1], x1, acc, 0, 0, 0);
            lg = fmaf(fmaxf(acc[0], 0.f), w2v4[nt].x, lg);
            lg = fmaf(fmaxf(acc[1], 0.f), w2v4[nt].y, lg);
            lg = fmaf(fmaxf(acc[2], 0.f), w2v4[nt].z, lg);
            lg = fmaf(fmaxf(acc[3], 0.f), w2v4[nt].w, lg);
        }
        lg += __shfl_xor(lg, 16, 64);               // sum over 4 qd groups
        lg += __shfl_xor(lg, 32, 64);
        return (p < NP) ? __expf(lg) : 0.f;         // plain exp (logits ~|1|)
    };

    // ---- 5 double iterations: tiles jA=2k, jB=2k+1 fully independent ----
    #pragma unroll
    for (int k = 0; k < 5; ++k) {
        half8 xA0, xA1, xB0, xB1;
        float eA = tile_e(2 * k,     xA0, xA1);
        float eB = tile_e(2 * k + 1, xB0, xB1);
        l += eA + eB;
        const _Float16 ehA = (_Float16)eA, ehB = (_Float16)eB;
        half8 a8 = { ehA, ehA, ehA, ehA, ehA, ehA, ehA, ehA };
        half8 b8 = { ehB, ehB, ehB, ehB, ehB, ehB, ehB, ehB };
        acc0 += xA0 * a8;  acc0 += xB0 * b8;        // v_pk_fma_f16
        acc1 += xA1 * a8;  acc1 += xB1 * b8;
    }
    // ---- leftover tile j=10 ----
    {
        half8 x0, x1;
        float e = tile_e(10, x0, x1);
        l += e;
        const _Float16 eh = (_Float16)e;
        half8 e8 = { eh, eh, eh, eh, eh, eh, eh, eh };
        acc0 += x0 * e8;
        acc1 += x1 * e8;
    }

    // ---- per-wave reduction to 2 scalars ----
    float lsum = l;                                  // sum over ln bits
    #pragma unroll
    for (int off = 1; off <= 8; off <<= 1) lsum += __shfl_xor(lsum, off, 64);

    float4 pa = *(const float4*)(proj + qd * 8);
    float4 pb = *(const float4*)(proj + qd * 8 + 4);
    float4 pc4 = *(const float4*)(proj + 32 + qd * 8);
    float4 pd = *(const float4*)(proj + 32 + qd * 8 + 4);
    float rrv = (float)acc0[0] * pa.x + (float)acc0[1] * pa.y
              + (float)acc0[2] * pa.z + (float)acc0[3] * pa.w
              + (float)acc0[4] * pb.x + (float)acc0[5] * pb.y
              + (float)acc0[6] * pb.z + (float)acc0[7] * pb.w
              + (float)acc1[0] * pc4.x + (float)acc1[1] * pc4.y
              + (float)acc1[2] * pc4.z + (float)acc1[3] * pc4.w
              + (float)acc1[4] * pd.x + (float)acc1[5] * pd.y
              + (float)acc1[6] * pd.z + (float)acc1[7] * pd.w;
    #pragma unroll
    for (int off = 1; off <= 32; off <<= 1) rrv += __shfl_xor(rrv, off, 64);

    if (lane == 0) { merge[wave][0] = rrv; merge[wave][1] = lsum; }

    __syncthreads();   // the only post-stage cross-wave coupling

    if (t == 0)
        out[r] = lin + (merge[0][0] + merge[1][0]) / (merge[0][1] + merge[1][1]);
}

extern "C" void kernel_launch(void* const* d_in, const int* in_sizes, int n_in,
                              void* d_out, int out_size, void* d_ws, size_t ws_size,
                              hipStream_t stream) {
    const int*   sparse = (const int*)  d_in[0];
    const float* dense  = (const float*)d_in[1];
    const float* etab   = (const float*)d_in[2];
    const float* ltab   = (const float*)d_in[3];
    const float* wdense = (const float*)d_in[4];
    const float* bias   = (const float*)d_in[5];
    const float* W1     = (const float*)d_in[6];
    const float* b1     = (const float*)d_in[7];
    const float* w2     = (const float*)d_in[8];
    const float* proj   = (const float*)d_in[9];
    float* outp = (float*)d_out;

    _Float16* w1t = (_Float16*)d_ws;   // 8192 B

    const int B = in_sizes[0] / NF;

    prep_kernel<<<dim3(1), dim3(256), 0, stream>>>(W1, w1t);
    afm_kernel<<<dim3(B), dim3(BLOCK), 0, stream>>>(
        sparse, dense, etab, ltab, wdense, bias, b1, w2, proj, w1t, outp);
    (void)n_in; (void)out_size; (void)ws_size;
}

// Round 12
// 127.399 us; speedup vs baseline: 1.2126x; 1.2126x over previous
//
#include <hip/hip_runtime.h>
#include <math.h>

// AFM forward: out[b] = linear(b) + softmax-weighted pair-interaction projection.
// B=4096, F=26, d=64, P=325 pairs, af=64.
//
// R12: R11's 2-tile-ILP kernel + amdgpu_waves_per_eu(2,4). R9/R11 post-mortem:
// with __launch_bounds__(128,4) the backend still TARGETS the default max
// 8 waves/EU -> 64-VGPR budget -> spills (VGPR pinned at exactly 64, WRITE
// 143 MB scratch). The launch-bounds 2nd arg only sets the MINIMUM. Capping
// the range from above (max 4 waves/EU) raises the register budget to 128+
// so the ~110-reg ILP-2 live set fits. 16 waves/CU occupancy is proven
// neutral for this kernel (R3 vs R5: 16 vs 32 waves/CU, same time).

#define NF 26
#define NP 325
#define NMT 21           // m-tiles of 16 pairs (336; pads contribute e=0)
#define ED 64
#define AF 64
#define NDENSE 13
#define BLOCK 128        // 2 waves, one row per block
#define ESTRIDE 72       // f16 elems per emb row (144 B: 16B-aligned, b128-clean)
#define EBYTES (ESTRIDE * 2)

typedef __attribute__((ext_vector_type(8))) _Float16 half8;
typedef __attribute__((ext_vector_type(4))) float f32x4;

__global__ void prep_kernel(const float* __restrict__ W1,
                            _Float16* __restrict__ w1t)   // [64][64] = W1^T, f16
{
    int t = threadIdx.x;
    for (int idx = t; idx < ED * AF; idx += 256) {
        int d = idx >> 6, a = idx & 63;       // W1 is [d][a]
        w1t[a * ED + d] = (_Float16)W1[idx];
    }
}

__global__ __launch_bounds__(BLOCK)
__attribute__((amdgpu_waves_per_eu(2, 4)))   // cap sched target: budget >=128 VGPR, no spill
void afm_kernel(const int*   __restrict__ sparse,   // [B,26]
                const float* __restrict__ dense,    // [B,13]
                const float* __restrict__ etab,     // [V,64]
                const float* __restrict__ ltab,     // [V]
                const float* __restrict__ wdense,   // [13]
                const float* __restrict__ bias,     // [1]
                const float* __restrict__ b1,       // [64]
                const float* __restrict__ w2,       // [64]
                const float* __restrict__ proj,     // [64]
                const _Float16* __restrict__ w1t,   // [64][64] f16 (a-major)
                float*       __restrict__ out)      // [B]
{
    const int t    = threadIdx.x;
    const int wave = t >> 6;
    const int lane = t & 63;
    const int qd   = lane >> 4;     // quad 0..3
    const int ln   = lane & 15;
    const int r    = blockIdx.x;    // this block's batch row

    __shared__ alignas(16) _Float16 emb[NF][ESTRIDE];   // 3744 B
    __shared__ float merge[2][2];                       // {rrv, lsum} per wave
    const char* __restrict__ ebase = (const char*)emb;

    // ---- stage this row's 26 embeddings FIRST (longest-latency gather) ----
    const int* __restrict__ srow = sparse + r * NF;
    for (int task = t; task < NF * 8; task += BLOCK) {
        int f = task >> 3, c = task & 7;                 // 8-half chunk
        const float* src = etab + (size_t)srow[f] * ED + c * 8;
        float4 v0 = *(const float4*)(src);
        float4 v1 = *(const float4*)(src + 4);
        half8 h = { (_Float16)v0.x, (_Float16)v0.y, (_Float16)v0.z, (_Float16)v0.w,
                    (_Float16)v1.x, (_Float16)v1.y, (_Float16)v1.z, (_Float16)v1.w };
        *(half8*)(&emb[f][c * 8]) = h;
    }

    // ---- W1^T A-operand fragments (L2-hot 8 KB):
    //      bfr[nt][kh] = w1t[af = nt*16+ln][k = kh*32 + qd*8 + j] ----
    half8 bfr[4][2];
    #pragma unroll
    for (int nt = 0; nt < 4; ++nt)
        #pragma unroll
        for (int kh = 0; kh < 2; ++kh)
            bfr[nt][kh] = *(const half8*)(w1t + (nt * 16 + ln) * ED + kh * 32 + qd * 8);

    // b1/w2 for af = nt*16 + qd*4 + rr  (C-row mapping)
    float4 b1v4[4], w2v4[4];
    #pragma unroll
    for (int nt = 0; nt < 4; ++nt) {
        b1v4[nt] = *(const float4*)(b1 + nt * 16 + qd * 4);
        w2v4[nt] = *(const float4*)(w2 + nt * 16 + qd * 4);
    }

    // ---- linear part (wave 0 registers; lands on t==0 which writes out) ----
    float lin = 0.f;
    if (wave == 0) {
        if (lane < NF) {
            lin = ltab[srow[lane]];
        } else if (lane >= 32 && lane < 32 + NDENSE) {
            int k = lane - 32;
            lin = dense[r * NDENSE + k] * wdense[k];
        }
        #pragma unroll
        for (int off = 32; off >= 1; off >>= 1) lin += __shfl_xor(lin, off, 64);
        lin += bias[0];
    }

    __syncthreads();   // emb visible (couples only 2 waves)

    const int qo0 = qd * 16;            // byte offsets within an emb row
    const int qo1 = 64 + qd * 16;

    float l = 0.f;
    half8 acc0 = { (_Float16)0.f, (_Float16)0.f, (_Float16)0.f, (_Float16)0.f,
                   (_Float16)0.f, (_Float16)0.f, (_Float16)0.f, (_Float16)0.f };
    half8 acc1 = acc0;

    // one m-tile's logit work; x0/x1 returned for the accumulator update
    auto tile_e = [&](int j, half8& x0, half8& x1) -> float {
        const int mt = 2 * j + wave;                // wave1 j=10 -> mt=21: dead, e=0
        const int p  = mt * 16 + ln;
        const int pc = (p < NP) ? p : 0;            // pad-safe decode input
        // closed-form triangular decode (exact in f32 for pc < 325; verified R9)
        const float sq = sqrtf((float)(2601 - 8 * pc));
        const int fi = (int)((51.0f - sq) * 0.5f);
        const int fj = fi + 1 + pc - ((fi * (51 - fi)) >> 1);
        const int oi = fi * EBYTES, oj = fj * EBYTES;

        half8 ei0 = *(const half8*)(ebase + oi + qo0);
        half8 ei1 = *(const half8*)(ebase + oi + qo1);
        half8 ej0 = *(const half8*)(ebase + oj + qo0);
        half8 ej1 = *(const half8*)(ebase + oj + qo1);
        x0 = ei0 * ej0;                             // pair product, in registers
        x1 = ei1 * ej1;

        // logits: D[m=af][n=pair=ln]; C rows = qd*4+reg = af within nt*16
        float lg = 0.f;
        #pragma unroll
        for (int nt = 0; nt < 4; ++nt) {
            f32x4 acc = { b1v4[nt].x, b1v4[nt].y, b1v4[nt].z, b1v4[nt].w };
            acc = __builtin_amdgcn_mfma_f32_16x16x32_f16(bfr[nt][0], x0, acc, 0, 0, 0);
            acc = __builtin_amdgcn_mfma_f32_16x16x32_f16(bfr[nt][1], x1, acc, 0, 0, 0);
            lg = fmaf(fmaxf(acc[0], 0.f), w2v4[nt].x, lg);
            lg = fmaf(fmaxf(acc[1], 0.f), w2v4[nt].y, lg);
            lg = fmaf(fmaxf(acc[2], 0.f), w2v4[nt].z, lg);
            lg = fmaf(fmaxf(acc[3], 0.f), w2v4[nt].w, lg);
        }
        lg += __shfl_xor(lg, 16, 64);               // sum over 4 qd groups
        lg += __shfl_xor(lg, 32, 64);
        return (p < NP) ? __expf(lg) : 0.f;         // plain exp (logits ~|1|)
    };

    // ---- 5 double iterations: tiles jA=2k, jB=2k+1 fully independent ----
    #pragma unroll
    for (int k = 0; k < 5; ++k) {
        half8 xA0, xA1, xB0, xB1;
        float eA = tile_e(2 * k,     xA0, xA1);
        float eB = tile_e(2 * k + 1, xB0, xB1);
        l += eA + eB;
        const _Float16 ehA = (_Float16)eA, ehB = (_Float16)eB;
        half8 a8 = { ehA, ehA, ehA, ehA, ehA, ehA, ehA, ehA };
        half8 b8 = { ehB, ehB, ehB, ehB, ehB, ehB, ehB, ehB };
        acc0 += xA0 * a8;  acc0 += xB0 * b8;        // v_pk_fma_f16
        acc1 += xA1 * a8;  acc1 += xB1 * b8;
    }
    // ---- leftover tile j=10 ----
    {
        half8 x0, x1;
        float e = tile_e(10, x0, x1);
        l += e;
        const _Float16 eh = (_Float16)e;
        half8 e8 = { eh, eh, eh, eh, eh, eh, eh, eh };
        acc0 += x0 * e8;
        acc1 += x1 * e8;
    }

    // ---- per-wave reduction to 2 scalars ----
    float lsum = l;                                  // sum over ln bits
    #pragma unroll
    for (int off = 1; off <= 8; off <<= 1) lsum += __shfl_xor(lsum, off, 64);

    float4 pa = *(const float4*)(proj + qd * 8);
    float4 pb = *(const float4*)(proj + qd * 8 + 4);
    float4 pc4 = *(const float4*)(proj + 32 + qd * 8);
    float4 pd = *(const float4*)(proj + 32 + qd * 8 + 4);
    float rrv = (float)acc0[0] * pa.x + (float)acc0[1] * pa.y
              + (float)acc0[2] * pa.z + (float)acc0[3] * pa.w
              + (float)acc0[4] * pb.x + (float)acc0[5] * pb.y
              + (float)acc0[6] * pb.z + (float)acc0[7] * pb.w
              + (float)acc1[0] * pc4.x + (float)acc1[1] * pc4.y
              + (float)acc1[2] * pc4.z + (float)acc1[3] * pc4.w
              + (float)acc1[4] * pd.x + (float)acc1[5] * pd.y
              + (float)acc1[6] * pd.z + (float)acc1[7] * pd.w;
    #pragma unroll
    for (int off = 1; off <= 32; off <<= 1) rrv += __shfl_xor(rrv, off, 64);

    if (lane == 0) { merge[wave][0] = rrv; merge[wave][1] = lsum; }

    __syncthreads();   // the only post-stage cross-wave coupling

    if (t == 0)
        out[r] = lin + (merge[0][0] + merge[1][0]) / (merge[0][1] + merge[1][1]);
}

extern "C" void kernel_launch(void* const* d_in, const int* in_sizes, int n_in,
                              void* d_out, int out_size, void* d_ws, size_t ws_size,
                              hipStream_t stream) {
    const int*   sparse = (const int*)  d_in[0];
    const float* dense  = (const float*)d_in[1];
    const float* etab   = (const float*)d_in[2];
    const float* ltab   = (const float*)d_in[3];
    const float* wdense = (const float*)d_in[4];
    const float* bias   = (const float*)d_in[5];
    const float* W1     = (const float*)d_in[6];
    const float* b1     = (const float*)d_in[7];
    const float* w2     = (const float*)d_in[8];
    const float* proj   = (const float*)d_in[9];
    float* outp = (float*)d_out;

    _Float16* w1t = (_Float16*)d_ws;   // 8192 B

    const int B = in_sizes[0] / NF;

    prep_kernel<<<dim3(1), dim3(256), 0, stream>>>(W1, w1t);
    afm_kernel<<<dim3(B), dim3(BLOCK), 0, stream>>>(
        sparse, dense, etab, ltab, wdense, bias, b1, w2, proj, w1t, outp);
    (void)n_in; (void)out_size; (void)ws_size;
}